// Round 4
// baseline (647.303 us; speedup 1.0000x reference)
//
#include <hip/hip_runtime.h>
#include <cmath>

// Transformer block (ViT): LN1 -> QKV -> MHA -> proj(+res) -> LN2 -> FC1+GELU -> FC2(+res)
// B=16, N=577, C=1024, H=16, D=64, HIDDEN=4096. fp32 in/out, fp16 MFMA compute.
// R1: XOR-swizzled LDS K-chunk placement (GEMM bank conflicts -> 0).
// R2: attention rewrite (gl_lds16 staging, 64-key tiles, exp2 softmax); tanh-GELU.
// R3: GEMM panel swizzle (GM=16 M-rows per panel, L2 A-tile reuse) + fp16 epilogue
//     LDS-transpose so stores are full-line half8 (write-combining 1.42x -> 1.0x).

#define MTOK 9232            // 16*577 valid token rows
#define MPAD 9344            // 73*128, padded for 128-row GEMM tiles
#define MT_TILES 73
#define SEQ  577
#define SEQP 640             // 10*64 padded key count
#define NKT  10

typedef _Float16 half8  __attribute__((ext_vector_type(8)));
typedef _Float16 half4  __attribute__((ext_vector_type(4)));
typedef float    float4v __attribute__((ext_vector_type(4)));

__device__ __forceinline__ void gl_lds16(const void* g, void* l) {
  __builtin_amdgcn_global_load_lds((const __attribute__((address_space(1))) void*)g,
                                   (__attribute__((address_space(3))) void*)l, 16, 0, 0);
}

__device__ __forceinline__ float fexp2(float x) { return __builtin_amdgcn_exp2f(x); }
__device__ __forceinline__ float frcp(float x)  { return __builtin_amdgcn_rcpf(x); }

// ---------------- fp32 -> fp16 convert (weights) ----------------
__global__ __launch_bounds__(256) void cvt_f16_kernel(const float* __restrict__ in,
                                                      _Float16* __restrict__ out, int n) {
  int i = (blockIdx.x * 256 + threadIdx.x) * 8;
  if (i >= n) return;
  float4v a = *(const float4v*)(in + i);
  float4v b = *(const float4v*)(in + i + 4);
  half8 o = { (_Float16)a[0], (_Float16)a[1], (_Float16)a[2], (_Float16)a[3],
              (_Float16)b[0], (_Float16)b[1], (_Float16)b[2], (_Float16)b[3] };
  *(half8*)(out + i) = o;
}

// ---------------- LayerNorm: fp32 in -> fp16 out, pad rows zeroed ----------------
__global__ __launch_bounds__(256) void ln_kernel(const float* __restrict__ x,
                                                 const float* __restrict__ gam,
                                                 const float* __restrict__ bet,
                                                 _Float16* __restrict__ out, int mrows) {
  int row = blockIdx.x, t = threadIdx.x;
  _Float16* orow = out + (long)row * 1024 + t * 4;
  if (row >= mrows) { half4 z = {}; *(half4*)orow = z; return; }
  float4v xv = *(const float4v*)(x + (long)row * 1024 + t * 4);
  float s  = xv[0] + xv[1] + xv[2] + xv[3];
  float ss = xv[0]*xv[0] + xv[1]*xv[1] + xv[2]*xv[2] + xv[3]*xv[3];
  #pragma unroll
  for (int o = 32; o > 0; o >>= 1) { s += __shfl_down(s, o); ss += __shfl_down(ss, o); }
  __shared__ float red[8];
  int w = t >> 6;
  if ((t & 63) == 0) { red[w] = s; red[4 + w] = ss; }
  __syncthreads();
  s  = red[0] + red[1] + red[2] + red[3];
  ss = red[4] + red[5] + red[6] + red[7];
  float mean = s * (1.0f / 1024.0f);
  float var  = ss * (1.0f / 1024.0f) - mean * mean;
  float rstd = rsqrtf(var + 1e-5f);
  float4v gv = *(const float4v*)(gam + t * 4);
  float4v bv = *(const float4v*)(bet + t * 4);
  half4 o;
  #pragma unroll
  for (int i = 0; i < 4; i++) o[i] = (_Float16)((xv[i] - mean) * rstd * gv[i] + bv[i]);
  *(half4*)orow = o;
}

// ---------------- GEMM: C[m,n] = sum_k A[m,k]*B[n,k] (+bias, epilogue) ----------------
// 1D grid, panel swizzle: GM=16 mt rows per panel, mt varies fastest (L2 A reuse).
// 128x128 tile, BK=64, 4 waves 2x2, 4x4 16x16x32 MFMA per wave. XOR-swizzled LDS.
// EPI: 0 = bias -> fp16; 1 = bias+GELU(tanh) -> fp16; 2 = bias+res -> fp32 (m<MTOK).
// fp16 epilogues go through an LDS transpose for full-line half8 global stores.
template <int EPI>
__global__ __launch_bounds__(256) void gemm_bt(const _Float16* __restrict__ A,
                                               const _Float16* __restrict__ Bw,
                                               const float* __restrict__ bias,
                                               const float* __restrict__ res,
                                               void* __restrict__ outv, int Ndim, int K) {
  __shared__ __align__(16) _Float16 SH[16384];     // As: [0,8192) Bs: [8192,16384)
  _Float16* As = SH;
  _Float16* Bs = SH + 8192;
  const int GM = 16;
  int nTiles = Ndim >> 7;
  int per = GM * nTiles;
  int lin = blockIdx.x;
  int panel = lin / per;
  int rem = lin - panel * per;
  int gm = MT_TILES - panel * GM; if (gm > GM) gm = GM;
  int mt = panel * GM + rem % gm;
  int nt = rem / gm;
  int t = threadIdx.x, w = t >> 6, l = t & 63;
  int wm = (w >> 1) * 64, wn = (w & 1) * 64;
  int g = l >> 4, li = l & 15;
  float4v acc[4][4] = {};
  const _Float16* aBase = A  + (long)mt * 128 * K;
  const _Float16* bBase = Bw + (long)nt * 128 * K;
  int nk = K >> 6;
  for (int kt = 0; kt < nk; ++kt) {
    const _Float16* ak = aBase + kt * 64;
    const _Float16* bk = bBase + kt * 64;
    #pragma unroll
    for (int r = 0; r < 4; ++r) {
      int idx = (w * 4 + r) * 64 + l;       // physical 16B slot id within the tile
      int row = idx >> 3;
      int kc  = (idx & 7) ^ (row & 7);      // XOR swizzle
      gl_lds16(ak + (long)row * K + kc * 8, As + (w * 4 + r) * 512);
      gl_lds16(bk + (long)row * K + kc * 8, Bs + (w * 4 + r) * 512);
    }
    __syncthreads();
    #pragma unroll
    for (int ks = 0; ks < 2; ++ks) {
      half8 af[4], bf[4];
      #pragma unroll
      for (int i = 0; i < 4; i++) {
        int ar = wm + i * 16 + li;
        af[i] = *(const half8*)(As + ar * 64 + (((ks * 4 + g) ^ (ar & 7)) * 8));
      }
      #pragma unroll
      for (int j = 0; j < 4; j++) {
        int br = wn + j * 16 + li;
        bf[j] = *(const half8*)(Bs + br * 64 + (((ks * 4 + g) ^ (br & 7)) * 8));
      }
      #pragma unroll
      for (int i = 0; i < 4; i++)
        #pragma unroll
        for (int j = 0; j < 4; j++)
          acc[i][j] = __builtin_amdgcn_mfma_f32_16x16x32_f16(af[i], bf[j], acc[i][j], 0, 0, 0);
    }
    __syncthreads();
  }
  // epilogue. C/D layout: col=lane&15, row=(lane>>4)*4+reg.
  if (EPI == 2) {
    #pragma unroll
    for (int j = 0; j < 4; ++j) {
      int col = nt * 128 + wn + j * 16 + li;
      float bsv = bias[col];
      #pragma unroll
      for (int i = 0; i < 4; ++i) {
        int row0 = mt * 128 + wm + i * 16 + g * 4;
        #pragma unroll
        for (int r = 0; r < 4; ++r) {
          int row = row0 + r;
          if (row < MTOK) {
            float v = acc[i][j][r] + bsv;
            ((float*)outv)[(long)row * Ndim + col] = v + res[(long)row * Ndim + col];
          }
        }
      }
    }
  } else {
    // fp16 out: LDS transpose, 2 passes of 64 cols; Sh[128][68] (pad 68 = conflict-free)
    _Float16* Sh = SH;
    float bsv[4];
    #pragma unroll
    for (int j = 0; j < 4; ++j) bsv[j] = bias[nt * 128 + wn + j * 16 + li];
    #pragma unroll
    for (int p = 0; p < 2; ++p) {
      if ((w & 1) == p) {
        #pragma unroll
        for (int i = 0; i < 4; ++i) {
          int rl = (w >> 1) * 64 + i * 16 + g * 4;
          #pragma unroll
          for (int j = 0; j < 4; ++j) {
            #pragma unroll
            for (int r = 0; r < 4; ++r) {
              float v = acc[i][j][r] + bsv[j];
              if (EPI == 1) {
                float y = v * (0.79788456f + 0.035677408f * v * v);
                v = v * frcp(1.0f + fexp2(-2.88539008f * y));
              }
              Sh[(rl + r) * 68 + j * 16 + li] = (_Float16)v;
            }
          }
        }
      }
      __syncthreads();
      #pragma unroll
      for (int cc = 0; cc < 4; ++cc) {
        int chunk = cc * 256 + t;
        int row = chunk >> 3, kc8 = chunk & 7;
        half8 hv = *(const half8*)(Sh + row * 68 + kc8 * 8);
        *(half8*)((_Float16*)outv + (long)(mt * 128 + row) * Ndim + nt * 128 + p * 64 + kc8 * 8) = hv;
      }
      __syncthreads();
    }
  }
}

// ---------------- V transpose: Qb V-part [key][d] -> Vt [bh][d][SEQP] fp16 ----------------
__global__ __launch_bounds__(256) void vt_kernel(const _Float16* __restrict__ qkv,
                                                 _Float16* __restrict__ Vt) {
  int kt = blockIdx.x, bh = blockIdx.y;
  int b = bh >> 4, h = bh & 15;
  long base = (long)b * SEQ;
  __shared__ _Float16 Lt[64][72];
  int t = threadIdx.x;
  #pragma unroll
  for (int c = t; c < 512; c += 256) {
    int key = c >> 3, dc = c & 7;
    int kglob = kt * 64 + key;
    half8 v = {};
    if (kglob < SEQ) v = *(const half8*)(qkv + (base + kglob) * 3072 + 2048 + h * 64 + dc * 8);
    *(half8*)(&Lt[key][dc * 8]) = v;
  }
  __syncthreads();
  #pragma unroll
  for (int c = t; c < 512; c += 256) {
    int d = c >> 3, kc = c & 7;
    half8 o;
    #pragma unroll
    for (int j = 0; j < 8; j++) o[j] = Lt[kc * 8 + j][d];
    *(half8*)(Vt + ((long)bh * 64 + d) * SEQP + kt * 64 + kc * 8) = o;
  }
}

// ---------------- Fused attention v2 ----------------
__global__ __launch_bounds__(256) void attn_kernel(const _Float16* __restrict__ qkv,
                                                   const _Float16* __restrict__ Vt,
                                                   _Float16* __restrict__ Y) {
  int qt = blockIdx.x, bh = blockIdx.y;
  int b = bh >> 4, h = bh & 15;
  long base = (long)b * SEQ;
  int t = threadIdx.x, w = t >> 6, l = t & 63;
  int g = l >> 4, li = l & 15;
  __shared__ __align__(16) _Float16 Ks[64 * 64];
  __shared__ __align__(16) _Float16 Vs[64 * 64];
  __shared__ __align__(16) _Float16 Pw[4][32 * 72];
  int q0 = qt * 128 + w * 32;
  half8 qf[2][2];
  #pragma unroll
  for (int m = 0; m < 2; ++m)
    #pragma unroll
    for (int ks = 0; ks < 2; ++ks)
      qf[m][ks] = *(const half8*)(qkv + (base + q0 + m * 16 + li) * 3072 + h * 64 + ks * 32 + g * 8);
  float4v o[2][4] = {};
  float mrow[2][4] = { { -1e30f, -1e30f, -1e30f, -1e30f }, { -1e30f, -1e30f, -1e30f, -1e30f } };
  float lrow[2][4] = {};
  const _Float16* vtb = Vt + (long)bh * 64 * SEQP;
  for (int kt = 0; kt < NKT; ++kt) {
    #pragma unroll
    for (int rr = 0; rr < 2; ++rr) {
      int idx = rr * 256 + w * 64 + l;
      int row = idx >> 3;
      int kc  = (idx & 7) ^ (row & 7);
      gl_lds16(qkv + (base + kt * 64 + row) * 3072 + 1024 + h * 64 + kc * 8,
               Ks + (rr * 256 + w * 64) * 8);
      gl_lds16(vtb + (long)row * SEQP + kt * 64 + kc * 8,
               Vs + (rr * 256 + w * 64) * 8);
    }
    __syncthreads();
    float4v s[2][4] = {};
    #pragma unroll
    for (int ks = 0; ks < 2; ++ks) {
      #pragma unroll
      for (int n = 0; n < 4; ++n) {
        int kr = n * 16 + li;
        half8 kf = *(const half8*)(Ks + kr * 64 + (((ks * 4 + g) ^ (kr & 7)) * 8));
        s[0][n] = __builtin_amdgcn_mfma_f32_16x16x32_f16(qf[0][ks], kf, s[0][n], 0, 0, 0);
        s[1][n] = __builtin_amdgcn_mfma_f32_16x16x32_f16(qf[1][ks], kf, s[1][n], 0, 0, 0);
      }
    }
    bool last = (kt == NKT - 1);
    const float sc = 0.125f * 1.44269504f;
    #pragma unroll
    for (int m = 0; m < 2; ++m) {
      #pragma unroll
      for (int r = 0; r < 4; ++r) {
        float v[4];
        #pragma unroll
        for (int n = 0; n < 4; ++n) {
          v[n] = s[m][n][r] * sc;
          if (last && (kt * 64 + n * 16 + li) >= SEQ) v[n] = -1e30f;
        }
        float a = fmaxf(fmaxf(v[0], v[1]), fmaxf(v[2], v[3]));
        a = fmaxf(a, __shfl_xor(a, 1));
        a = fmaxf(a, __shfl_xor(a, 2));
        a = fmaxf(a, __shfl_xor(a, 4));
        a = fmaxf(a, __shfl_xor(a, 8));
        float mn = fmaxf(mrow[m][r], a);
        float al = fexp2(mrow[m][r] - mn);
        mrow[m][r] = mn;
        int prow = m * 16 + g * 4 + r;
        float rs = 0.f;
        #pragma unroll
        for (int n = 0; n < 4; ++n) {
          float p = fexp2(v[n] - mn);
          rs += p;
          Pw[w][prow * 72 + n * 16 + li] = (_Float16)p;
        }
        rs += __shfl_xor(rs, 1);
        rs += __shfl_xor(rs, 2);
        rs += __shfl_xor(rs, 4);
        rs += __shfl_xor(rs, 8);
        lrow[m][r] = lrow[m][r] * al + rs;
        #pragma unroll
        for (int n = 0; n < 4; ++n) o[m][n][r] *= al;
      }
    }
    #pragma unroll
    for (int ks = 0; ks < 2; ++ks) {
      half8 pa[2];
      #pragma unroll
      for (int m = 0; m < 2; ++m)
        pa[m] = *(const half8*)(&Pw[w][(m * 16 + li) * 72 + ks * 32 + g * 8]);
      #pragma unroll
      for (int n = 0; n < 4; ++n) {
        int vr = n * 16 + li;
        half8 vf = *(const half8*)(Vs + vr * 64 + (((ks * 4 + g) ^ (vr & 7)) * 8));
        o[0][n] = __builtin_amdgcn_mfma_f32_16x16x32_f16(pa[0], vf, o[0][n], 0, 0, 0);
        o[1][n] = __builtin_amdgcn_mfma_f32_16x16x32_f16(pa[1], vf, o[1][n], 0, 0, 0);
      }
    }
    __syncthreads();
  }
  #pragma unroll
  for (int m = 0; m < 2; ++m) {
    #pragma unroll
    for (int r = 0; r < 4; ++r) {
      int qr = q0 + m * 16 + g * 4 + r;
      if (qr < SEQ) {
        float inv = frcp(lrow[m][r]);
        _Float16* yp = Y + (base + qr) * 1024 + h * 64 + li;
        #pragma unroll
        for (int n = 0; n < 4; ++n) yp[n * 16] = (_Float16)(o[m][n][r] * inv);
      }
    }
  }
}

extern "C" void kernel_launch(void* const* d_in, const int* in_sizes, int n_in,
                              void* d_out, int out_size, void* d_ws, size_t ws_size,
                              hipStream_t stream) {
  (void)in_sizes; (void)n_in; (void)out_size; (void)ws_size;
  const float* x      = (const float*)d_in[0];
  const float* w_qkv  = (const float*)d_in[1];
  const float* b_qkv  = (const float*)d_in[2];
  const float* w_proj = (const float*)d_in[3];
  const float* b_proj = (const float*)d_in[4];
  const float* ln1_g  = (const float*)d_in[5];
  const float* ln1_b  = (const float*)d_in[6];
  const float* ln2_g  = (const float*)d_in[7];
  const float* ln2_b  = (const float*)d_in[8];
  const float* w_fc1  = (const float*)d_in[9];
  const float* b_fc1  = (const float*)d_in[10];
  const float* w_fc2  = (const float*)d_in[11];
  const float* b_fc2  = (const float*)d_in[12];

  char* ws = (char*)d_ws;
  _Float16* Abuf = (_Float16*)ws;                          // [MPAD][1024] act fp16
  _Float16* Wq   = (_Float16*)(ws + 19136512);             // weights fp16
  _Float16* Wp   = Wq + 3072 * 1024;
  _Float16* W1   = Wp + 1024 * 1024;
  _Float16* W2   = W1 + 4096 * 1024;
  _Float16* Qb   = (_Float16*)(ws + 44302336);             // [MPAD][3072] qkv fp16
  _Float16* Yb   = Qb + (long)MPAD * 3072;                 // [MPAD][1024] attn out fp16
  _Float16* Hb   = Qb;                                     // [MPAD][4096] fp16, reuses Qb+Yb
  float*    X1   = (float*)(ws + 120848384);               // [MPAD][1024] fp32 x+attn
  _Float16* Vtb  = (_Float16*)(ws + 120848384);            // [256][64][SEQP] fp16, overlays X1

  cvt_f16_kernel<<<1536, 256, 0, stream>>>(w_qkv, Wq, 3072 * 1024);
  cvt_f16_kernel<<<512,  256, 0, stream>>>(w_proj, Wp, 1024 * 1024);
  cvt_f16_kernel<<<2048, 256, 0, stream>>>(w_fc1, W1, 4096 * 1024);
  cvt_f16_kernel<<<2048, 256, 0, stream>>>(w_fc2, W2, 4096 * 1024);

  ln_kernel<<<MPAD, 256, 0, stream>>>(x, ln1_g, ln1_b, Abuf, MTOK);
  gemm_bt<0><<<73 * 24, 256, 0, stream>>>(Abuf, Wq, b_qkv, nullptr, Qb, 3072, 1024);
  vt_kernel<<<dim3(NKT, 256), 256, 0, stream>>>(Qb, Vtb);
  attn_kernel<<<dim3(5, 256), 256, 0, stream>>>(Qb, Vtb, Yb);
  gemm_bt<2><<<73 * 8, 256, 0, stream>>>(Yb, Wp, b_proj, x, X1, 1024, 1024);
  ln_kernel<<<MPAD, 256, 0, stream>>>(X1, ln2_g, ln2_b, Abuf, MTOK);
  gemm_bt<1><<<73 * 32, 256, 0, stream>>>(Abuf, W1, b_fc1, nullptr, Hb, 4096, 1024);
  gemm_bt<2><<<73 * 8, 256, 0, stream>>>(Hb, W2, b_fc2, X1, d_out, 1024, 4096);
}

// Round 5
// 620.602 us; speedup vs baseline: 1.0430x; 1.0430x over previous
//
#include <hip/hip_runtime.h>
#include <cmath>

// Transformer block (ViT): LN1 -> QKV -> MHA -> proj(+res) -> LN2 -> FC1+GELU -> FC2(+res)
// B=16, N=577, C=1024, H=16, D=64, HIDDEN=4096. fp32 in/out, fp16 MFMA compute.
// R1: XOR-swizzled LDS K-chunk placement (GEMM bank conflicts -> 0).
// R2: attention rewrite (gl_lds16 staging, 64-key tiles, exp2 softmax); tanh-GELU.
// R3: GEMM panel swizzle (GM=16) + fp16 epilogue LDS-transpose (full-line half8 stores).
// R4: EPI=2 (fp32 + residual) epilogue through LDS too: 4x 32-col passes, float4
//     res/bias loads + float4 stores (full 128B lines); single fused cvt kernel.

#define MTOK 9232            // 16*577 valid token rows
#define MPAD 9344            // 73*128, padded for 128-row GEMM tiles
#define MT_TILES 73
#define SEQ  577
#define SEQP 640             // 10*64 padded key count
#define NKT  10

typedef _Float16 half8  __attribute__((ext_vector_type(8)));
typedef _Float16 half4  __attribute__((ext_vector_type(4)));
typedef float    float4v __attribute__((ext_vector_type(4)));

__device__ __forceinline__ void gl_lds16(const void* g, void* l) {
  __builtin_amdgcn_global_load_lds((const __attribute__((address_space(1))) void*)g,
                                   (__attribute__((address_space(3))) void*)l, 16, 0, 0);
}

__device__ __forceinline__ float fexp2(float x) { return __builtin_amdgcn_exp2f(x); }
__device__ __forceinline__ float frcp(float x)  { return __builtin_amdgcn_rcpf(x); }

// ---------------- fp32 -> fp16 convert, all 4 weight mats in one launch ----------------
__global__ __launch_bounds__(256) void cvt_all_kernel(const float* __restrict__ s0, _Float16* __restrict__ d0,
                                                      const float* __restrict__ s1, _Float16* __restrict__ d1,
                                                      const float* __restrict__ s2, _Float16* __restrict__ d2,
                                                      const float* __restrict__ s3, _Float16* __restrict__ d3) {
  // region sizes in 8-elem chunks per 256-thread block: 1536 / 512 / 2048 / 2048 blocks
  int blk = blockIdx.x;
  const float* in; _Float16* out; int base;
  if (blk < 1536)      { in = s0; out = d0; base = blk; }
  else if (blk < 2048) { in = s1; out = d1; base = blk - 1536; }
  else if (blk < 4096) { in = s2; out = d2; base = blk - 2048; }
  else                 { in = s3; out = d3; base = blk - 4096; }
  int i = (base * 256 + threadIdx.x) * 8;
  float4v a = *(const float4v*)(in + i);
  float4v b = *(const float4v*)(in + i + 4);
  half8 o = { (_Float16)a[0], (_Float16)a[1], (_Float16)a[2], (_Float16)a[3],
              (_Float16)b[0], (_Float16)b[1], (_Float16)b[2], (_Float16)b[3] };
  *(half8*)(out + i) = o;
}

// ---------------- LayerNorm: fp32 in -> fp16 out, pad rows zeroed ----------------
__global__ __launch_bounds__(256) void ln_kernel(const float* __restrict__ x,
                                                 const float* __restrict__ gam,
                                                 const float* __restrict__ bet,
                                                 _Float16* __restrict__ out, int mrows) {
  int row = blockIdx.x, t = threadIdx.x;
  _Float16* orow = out + (long)row * 1024 + t * 4;
  if (row >= mrows) { half4 z = {}; *(half4*)orow = z; return; }
  float4v xv = *(const float4v*)(x + (long)row * 1024 + t * 4);
  float s  = xv[0] + xv[1] + xv[2] + xv[3];
  float ss = xv[0]*xv[0] + xv[1]*xv[1] + xv[2]*xv[2] + xv[3]*xv[3];
  #pragma unroll
  for (int o = 32; o > 0; o >>= 1) { s += __shfl_down(s, o); ss += __shfl_down(ss, o); }
  __shared__ float red[8];
  int w = t >> 6;
  if ((t & 63) == 0) { red[w] = s; red[4 + w] = ss; }
  __syncthreads();
  s  = red[0] + red[1] + red[2] + red[3];
  ss = red[4] + red[5] + red[6] + red[7];
  float mean = s * (1.0f / 1024.0f);
  float var  = ss * (1.0f / 1024.0f) - mean * mean;
  float rstd = rsqrtf(var + 1e-5f);
  float4v gv = *(const float4v*)(gam + t * 4);
  float4v bv = *(const float4v*)(bet + t * 4);
  half4 o;
  #pragma unroll
  for (int i = 0; i < 4; i++) o[i] = (_Float16)((xv[i] - mean) * rstd * gv[i] + bv[i]);
  *(half4*)orow = o;
}

// ---------------- GEMM: C[m,n] = sum_k A[m,k]*B[n,k] (+bias, epilogue) ----------------
// 1D grid, panel swizzle: GM=16 mt rows per panel, mt varies fastest (L2 A reuse).
// 128x128 tile, BK=64, 4 waves 2x2, 4x4 16x16x32 MFMA per wave. XOR-swizzled LDS.
// EPI: 0 = bias -> fp16; 1 = bias+GELU(tanh) -> fp16; 2 = bias+res -> fp32 (m<MTOK).
// All epilogues bounce through LDS for full-line vector global stores.
template <int EPI>
__global__ __launch_bounds__(256) void gemm_bt(const _Float16* __restrict__ A,
                                               const _Float16* __restrict__ Bw,
                                               const float* __restrict__ bias,
                                               const float* __restrict__ res,
                                               void* __restrict__ outv, int Ndim, int K) {
  __shared__ __align__(16) _Float16 SH[16384];     // As: [0,8192) Bs: [8192,16384)
  _Float16* As = SH;
  _Float16* Bs = SH + 8192;
  const int GM = 16;
  int nTiles = Ndim >> 7;
  int per = GM * nTiles;
  int lin = blockIdx.x;
  int panel = lin / per;
  int rem = lin - panel * per;
  int gm = MT_TILES - panel * GM; if (gm > GM) gm = GM;
  int mt = panel * GM + rem % gm;
  int nt = rem / gm;
  int t = threadIdx.x, w = t >> 6, l = t & 63;
  int wm = (w >> 1) * 64, wn = (w & 1) * 64;
  int g = l >> 4, li = l & 15;
  float4v acc[4][4] = {};
  const _Float16* aBase = A  + (long)mt * 128 * K;
  const _Float16* bBase = Bw + (long)nt * 128 * K;
  int nk = K >> 6;
  for (int kt = 0; kt < nk; ++kt) {
    const _Float16* ak = aBase + kt * 64;
    const _Float16* bk = bBase + kt * 64;
    #pragma unroll
    for (int r = 0; r < 4; ++r) {
      int idx = (w * 4 + r) * 64 + l;       // physical 16B slot id within the tile
      int row = idx >> 3;
      int kc  = (idx & 7) ^ (row & 7);      // XOR swizzle
      gl_lds16(ak + (long)row * K + kc * 8, As + (w * 4 + r) * 512);
      gl_lds16(bk + (long)row * K + kc * 8, Bs + (w * 4 + r) * 512);
    }
    __syncthreads();
    #pragma unroll
    for (int ks = 0; ks < 2; ++ks) {
      half8 af[4], bf[4];
      #pragma unroll
      for (int i = 0; i < 4; i++) {
        int ar = wm + i * 16 + li;
        af[i] = *(const half8*)(As + ar * 64 + (((ks * 4 + g) ^ (ar & 7)) * 8));
      }
      #pragma unroll
      for (int j = 0; j < 4; j++) {
        int br = wn + j * 16 + li;
        bf[j] = *(const half8*)(Bs + br * 64 + (((ks * 4 + g) ^ (br & 7)) * 8));
      }
      #pragma unroll
      for (int i = 0; i < 4; i++)
        #pragma unroll
        for (int j = 0; j < 4; j++)
          acc[i][j] = __builtin_amdgcn_mfma_f32_16x16x32_f16(af[i], bf[j], acc[i][j], 0, 0, 0);
    }
    __syncthreads();
  }
  // epilogue. C/D layout: col=lane&15, row=(lane>>4)*4+reg.
  if (EPI == 2) {
    // fp32 + bias + residual, through LDS: 4 passes of 32 cols, float4 I/O.
    float* Shf = (float*)SH;                       // [128][36] floats = 18 KB
    #pragma unroll
    for (int p = 0; p < 4; ++p) {
      if ((w & 1) == (p >> 1)) {                   // this wave's wn-half owns these cols
        int j0 = (p & 1) * 2;
        #pragma unroll
        for (int i = 0; i < 4; ++i) {
          #pragma unroll
          for (int jj = 0; jj < 2; ++jj) {
            #pragma unroll
            for (int r = 0; r < 4; ++r) {
              int row = wm + i * 16 + g * 4 + r;
              Shf[row * 36 + jj * 16 + li] = acc[i][j0 + jj][r];
            }
          }
        }
      }
      __syncthreads();
      #pragma unroll
      for (int it = 0; it < 4; ++it) {
        int chunk = it * 256 + t;
        int row = chunk >> 3, c4 = chunk & 7;
        int grow = mt * 128 + row;
        if (grow < MTOK) {
          float4v v = *(const float4v*)(Shf + row * 36 + c4 * 4);
          int gcol = nt * 128 + p * 32 + c4 * 4;
          float4v bv = *(const float4v*)(bias + gcol);
          float4v rv = *(const float4v*)(res + (long)grow * Ndim + gcol);
          v = v + bv + rv;
          *(float4v*)((float*)outv + (long)grow * Ndim + gcol) = v;
        }
      }
      __syncthreads();
    }
  } else {
    // fp16 out: LDS transpose, 2 passes of 64 cols; Sh[128][68] (pad 68 = conflict-free)
    _Float16* Sh = SH;
    float bsv[4];
    #pragma unroll
    for (int j = 0; j < 4; ++j) bsv[j] = bias[nt * 128 + wn + j * 16 + li];
    #pragma unroll
    for (int p = 0; p < 2; ++p) {
      if ((w & 1) == p) {
        #pragma unroll
        for (int i = 0; i < 4; ++i) {
          int rl = (w >> 1) * 64 + i * 16 + g * 4;
          #pragma unroll
          for (int j = 0; j < 4; ++j) {
            #pragma unroll
            for (int r = 0; r < 4; ++r) {
              float v = acc[i][j][r] + bsv[j];
              if (EPI == 1) {
                float y = v * (0.79788456f + 0.035677408f * v * v);
                v = v * frcp(1.0f + fexp2(-2.88539008f * y));
              }
              Sh[(rl + r) * 68 + j * 16 + li] = (_Float16)v;
            }
          }
        }
      }
      __syncthreads();
      #pragma unroll
      for (int cc = 0; cc < 4; ++cc) {
        int chunk = cc * 256 + t;
        int row = chunk >> 3, kc8 = chunk & 7;
        half8 hv = *(const half8*)(Sh + row * 68 + kc8 * 8);
        *(half8*)((_Float16*)outv + (long)(mt * 128 + row) * Ndim + nt * 128 + p * 64 + kc8 * 8) = hv;
      }
      __syncthreads();
    }
  }
}

// ---------------- V transpose: Qb V-part [key][d] -> Vt [bh][d][SEQP] fp16 ----------------
__global__ __launch_bounds__(256) void vt_kernel(const _Float16* __restrict__ qkv,
                                                 _Float16* __restrict__ Vt) {
  int kt = blockIdx.x, bh = blockIdx.y;
  int b = bh >> 4, h = bh & 15;
  long base = (long)b * SEQ;
  __shared__ _Float16 Lt[64][72];
  int t = threadIdx.x;
  #pragma unroll
  for (int c = t; c < 512; c += 256) {
    int key = c >> 3, dc = c & 7;
    int kglob = kt * 64 + key;
    half8 v = {};
    if (kglob < SEQ) v = *(const half8*)(qkv + (base + kglob) * 3072 + 2048 + h * 64 + dc * 8);
    *(half8*)(&Lt[key][dc * 8]) = v;
  }
  __syncthreads();
  #pragma unroll
  for (int c = t; c < 512; c += 256) {
    int d = c >> 3, kc = c & 7;
    half8 o;
    #pragma unroll
    for (int j = 0; j < 8; j++) o[j] = Lt[kc * 8 + j][d];
    *(half8*)(Vt + ((long)bh * 64 + d) * SEQP + kt * 64 + kc * 8) = o;
  }
}

// ---------------- Fused attention v2 ----------------
__global__ __launch_bounds__(256) void attn_kernel(const _Float16* __restrict__ qkv,
                                                   const _Float16* __restrict__ Vt,
                                                   _Float16* __restrict__ Y) {
  int qt = blockIdx.x, bh = blockIdx.y;
  int b = bh >> 4, h = bh & 15;
  long base = (long)b * SEQ;
  int t = threadIdx.x, w = t >> 6, l = t & 63;
  int g = l >> 4, li = l & 15;
  __shared__ __align__(16) _Float16 Ks[64 * 64];
  __shared__ __align__(16) _Float16 Vs[64 * 64];
  __shared__ __align__(16) _Float16 Pw[4][32 * 72];
  int q0 = qt * 128 + w * 32;
  half8 qf[2][2];
  #pragma unroll
  for (int m = 0; m < 2; ++m)
    #pragma unroll
    for (int ks = 0; ks < 2; ++ks)
      qf[m][ks] = *(const half8*)(qkv + (base + q0 + m * 16 + li) * 3072 + h * 64 + ks * 32 + g * 8);
  float4v o[2][4] = {};
  float mrow[2][4] = { { -1e30f, -1e30f, -1e30f, -1e30f }, { -1e30f, -1e30f, -1e30f, -1e30f } };
  float lrow[2][4] = {};
  const _Float16* vtb = Vt + (long)bh * 64 * SEQP;
  for (int kt = 0; kt < NKT; ++kt) {
    #pragma unroll
    for (int rr = 0; rr < 2; ++rr) {
      int idx = rr * 256 + w * 64 + l;
      int row = idx >> 3;
      int kc  = (idx & 7) ^ (row & 7);
      gl_lds16(qkv + (base + kt * 64 + row) * 3072 + 1024 + h * 64 + kc * 8,
               Ks + (rr * 256 + w * 64) * 8);
      gl_lds16(vtb + (long)row * SEQP + kt * 64 + kc * 8,
               Vs + (rr * 256 + w * 64) * 8);
    }
    __syncthreads();
    float4v s[2][4] = {};
    #pragma unroll
    for (int ks = 0; ks < 2; ++ks) {
      #pragma unroll
      for (int n = 0; n < 4; ++n) {
        int kr = n * 16 + li;
        half8 kf = *(const half8*)(Ks + kr * 64 + (((ks * 4 + g) ^ (kr & 7)) * 8));
        s[0][n] = __builtin_amdgcn_mfma_f32_16x16x32_f16(qf[0][ks], kf, s[0][n], 0, 0, 0);
        s[1][n] = __builtin_amdgcn_mfma_f32_16x16x32_f16(qf[1][ks], kf, s[1][n], 0, 0, 0);
      }
    }
    bool last = (kt == NKT - 1);
    const float sc = 0.125f * 1.44269504f;
    #pragma unroll
    for (int m = 0; m < 2; ++m) {
      #pragma unroll
      for (int r = 0; r < 4; ++r) {
        float v[4];
        #pragma unroll
        for (int n = 0; n < 4; ++n) {
          v[n] = s[m][n][r] * sc;
          if (last && (kt * 64 + n * 16 + li) >= SEQ) v[n] = -1e30f;
        }
        float a = fmaxf(fmaxf(v[0], v[1]), fmaxf(v[2], v[3]));
        a = fmaxf(a, __shfl_xor(a, 1));
        a = fmaxf(a, __shfl_xor(a, 2));
        a = fmaxf(a, __shfl_xor(a, 4));
        a = fmaxf(a, __shfl_xor(a, 8));
        float mn = fmaxf(mrow[m][r], a);
        float al = fexp2(mrow[m][r] - mn);
        mrow[m][r] = mn;
        int prow = m * 16 + g * 4 + r;
        float rs = 0.f;
        #pragma unroll
        for (int n = 0; n < 4; ++n) {
          float p = fexp2(v[n] - mn);
          rs += p;
          Pw[w][prow * 72 + n * 16 + li] = (_Float16)p;
        }
        rs += __shfl_xor(rs, 1);
        rs += __shfl_xor(rs, 2);
        rs += __shfl_xor(rs, 4);
        rs += __shfl_xor(rs, 8);
        lrow[m][r] = lrow[m][r] * al + rs;
        #pragma unroll
        for (int n = 0; n < 4; ++n) o[m][n][r] *= al;
      }
    }
    #pragma unroll
    for (int ks = 0; ks < 2; ++ks) {
      half8 pa[2];
      #pragma unroll
      for (int m = 0; m < 2; ++m)
        pa[m] = *(const half8*)(&Pw[w][(m * 16 + li) * 72 + ks * 32 + g * 8]);
      #pragma unroll
      for (int n = 0; n < 4; ++n) {
        int vr = n * 16 + li;
        half8 vf = *(const half8*)(Vs + vr * 64 + (((ks * 4 + g) ^ (vr & 7)) * 8));
        o[0][n] = __builtin_amdgcn_mfma_f32_16x16x32_f16(pa[0], vf, o[0][n], 0, 0, 0);
        o[1][n] = __builtin_amdgcn_mfma_f32_16x16x32_f16(pa[1], vf, o[1][n], 0, 0, 0);
      }
    }
    __syncthreads();
  }
  #pragma unroll
  for (int m = 0; m < 2; ++m) {
    #pragma unroll
    for (int r = 0; r < 4; ++r) {
      int qr = q0 + m * 16 + g * 4 + r;
      if (qr < SEQ) {
        float inv = frcp(lrow[m][r]);
        _Float16* yp = Y + (base + qr) * 1024 + h * 64 + li;
        #pragma unroll
        for (int n = 0; n < 4; ++n) yp[n * 16] = (_Float16)(o[m][n][r] * inv);
      }
    }
  }
}

extern "C" void kernel_launch(void* const* d_in, const int* in_sizes, int n_in,
                              void* d_out, int out_size, void* d_ws, size_t ws_size,
                              hipStream_t stream) {
  (void)in_sizes; (void)n_in; (void)out_size; (void)ws_size;
  const float* x      = (const float*)d_in[0];
  const float* w_qkv  = (const float*)d_in[1];
  const float* b_qkv  = (const float*)d_in[2];
  const float* w_proj = (const float*)d_in[3];
  const float* b_proj = (const float*)d_in[4];
  const float* ln1_g  = (const float*)d_in[5];
  const float* ln1_b  = (const float*)d_in[6];
  const float* ln2_g  = (const float*)d_in[7];
  const float* ln2_b  = (const float*)d_in[8];
  const float* w_fc1  = (const float*)d_in[9];
  const float* b_fc1  = (const float*)d_in[10];
  const float* w_fc2  = (const float*)d_in[11];
  const float* b_fc2  = (const float*)d_in[12];

  char* ws = (char*)d_ws;
  _Float16* Abuf = (_Float16*)ws;                          // [MPAD][1024] act fp16
  _Float16* Wq   = (_Float16*)(ws + 19136512);             // weights fp16
  _Float16* Wp   = Wq + 3072 * 1024;
  _Float16* W1   = Wp + 1024 * 1024;
  _Float16* W2   = W1 + 4096 * 1024;
  _Float16* Qb   = (_Float16*)(ws + 44302336);             // [MPAD][3072] qkv fp16
  _Float16* Yb   = Qb + (long)MPAD * 3072;                 // [MPAD][1024] attn out fp16
  _Float16* Hb   = Qb;                                     // [MPAD][4096] fp16, reuses Qb+Yb
  float*    X1   = (float*)(ws + 120848384);               // [MPAD][1024] fp32 x+attn
  _Float16* Vtb  = (_Float16*)(ws + 120848384);            // [256][64][SEQP] fp16, overlays X1

  cvt_all_kernel<<<6144, 256, 0, stream>>>(w_qkv, Wq, w_proj, Wp, w_fc1, W1, w_fc2, W2);

  ln_kernel<<<MPAD, 256, 0, stream>>>(x, ln1_g, ln1_b, Abuf, MTOK);
  gemm_bt<0><<<73 * 24, 256, 0, stream>>>(Abuf, Wq, b_qkv, nullptr, Qb, 3072, 1024);
  vt_kernel<<<dim3(NKT, 256), 256, 0, stream>>>(Qb, Vtb);
  attn_kernel<<<dim3(5, 256), 256, 0, stream>>>(Qb, Vtb, Yb);
  gemm_bt<2><<<73 * 8, 256, 0, stream>>>(Yb, Wp, b_proj, x, X1, 1024, 1024);
  ln_kernel<<<MPAD, 256, 0, stream>>>(X1, ln2_g, ln2_b, Abuf, MTOK);
  gemm_bt<1><<<73 * 32, 256, 0, stream>>>(Abuf, W1, b_fc1, nullptr, Hb, 4096, 1024);
  gemm_bt<2><<<73 * 8, 256, 0, stream>>>(Hb, W2, b_fc2, X1, d_out, 1024, 4096);
}

// Round 6
// 545.435 us; speedup vs baseline: 1.1868x; 1.1378x over previous
//
#include <hip/hip_runtime.h>
#include <cmath>

// Transformer block (ViT): LN1 -> QKV -> MHA -> proj(+res) -> LN2 -> FC1+GELU -> FC2(+res)
// B=16, N=577, C=1024, H=16, D=64, HIDDEN=4096. fp32 in/out, fp16 MFMA compute.
// R1: XOR-swizzled LDS K-chunk placement (GEMM bank conflicts -> 0).
// R2: attention rewrite (gl_lds16 staging, 64-key tiles, exp2 softmax); tanh-GELU.
// R3: GEMM panel swizzle (GM=16) + fp16 epilogue LDS-transpose (full-line half8 stores).
// R4: EPI=2 epilogue through LDS (float4 full-line I/O); single fused cvt kernel.
// R5: hoist all loop-invariant GEMM address math out of the K-loop (staging offsets +
//     16 swizzled LDS read offsets) and raise VGPR budget via __launch_bounds__(256,3)
//     so the compiler keeps them live instead of rematerializing (VALUBusy 45%).

#define MTOK 9232            // 16*577 valid token rows
#define MPAD 9344            // 73*128, padded for 128-row GEMM tiles
#define MT_TILES 73
#define SEQ  577
#define SEQP 640             // 10*64 padded key count
#define NKT  10

typedef _Float16 half8  __attribute__((ext_vector_type(8)));
typedef _Float16 half4  __attribute__((ext_vector_type(4)));
typedef float    float4v __attribute__((ext_vector_type(4)));

__device__ __forceinline__ void gl_lds16(const void* g, void* l) {
  __builtin_amdgcn_global_load_lds((const __attribute__((address_space(1))) void*)g,
                                   (__attribute__((address_space(3))) void*)l, 16, 0, 0);
}

__device__ __forceinline__ float fexp2(float x) { return __builtin_amdgcn_exp2f(x); }
__device__ __forceinline__ float frcp(float x)  { return __builtin_amdgcn_rcpf(x); }

// ---------------- fp32 -> fp16 convert, all 4 weight mats in one launch ----------------
__global__ __launch_bounds__(256) void cvt_all_kernel(const float* __restrict__ s0, _Float16* __restrict__ d0,
                                                      const float* __restrict__ s1, _Float16* __restrict__ d1,
                                                      const float* __restrict__ s2, _Float16* __restrict__ d2,
                                                      const float* __restrict__ s3, _Float16* __restrict__ d3) {
  int blk = blockIdx.x;
  const float* in; _Float16* out; int base;
  if (blk < 1536)      { in = s0; out = d0; base = blk; }
  else if (blk < 2048) { in = s1; out = d1; base = blk - 1536; }
  else if (blk < 4096) { in = s2; out = d2; base = blk - 2048; }
  else                 { in = s3; out = d3; base = blk - 4096; }
  int i = (base * 256 + threadIdx.x) * 8;
  float4v a = *(const float4v*)(in + i);
  float4v b = *(const float4v*)(in + i + 4);
  half8 o = { (_Float16)a[0], (_Float16)a[1], (_Float16)a[2], (_Float16)a[3],
              (_Float16)b[0], (_Float16)b[1], (_Float16)b[2], (_Float16)b[3] };
  *(half8*)(out + i) = o;
}

// ---------------- LayerNorm: fp32 in -> fp16 out, pad rows zeroed ----------------
__global__ __launch_bounds__(256) void ln_kernel(const float* __restrict__ x,
                                                 const float* __restrict__ gam,
                                                 const float* __restrict__ bet,
                                                 _Float16* __restrict__ out, int mrows) {
  int row = blockIdx.x, t = threadIdx.x;
  _Float16* orow = out + (long)row * 1024 + t * 4;
  if (row >= mrows) { half4 z = {}; *(half4*)orow = z; return; }
  float4v xv = *(const float4v*)(x + (long)row * 1024 + t * 4);
  float s  = xv[0] + xv[1] + xv[2] + xv[3];
  float ss = xv[0]*xv[0] + xv[1]*xv[1] + xv[2]*xv[2] + xv[3]*xv[3];
  #pragma unroll
  for (int o = 32; o > 0; o >>= 1) { s += __shfl_down(s, o); ss += __shfl_down(ss, o); }
  __shared__ float red[8];
  int w = t >> 6;
  if ((t & 63) == 0) { red[w] = s; red[4 + w] = ss; }
  __syncthreads();
  s  = red[0] + red[1] + red[2] + red[3];
  ss = red[4] + red[5] + red[6] + red[7];
  float mean = s * (1.0f / 1024.0f);
  float var  = ss * (1.0f / 1024.0f) - mean * mean;
  float rstd = rsqrtf(var + 1e-5f);
  float4v gv = *(const float4v*)(gam + t * 4);
  float4v bv = *(const float4v*)(bet + t * 4);
  half4 o;
  #pragma unroll
  for (int i = 0; i < 4; i++) o[i] = (_Float16)((xv[i] - mean) * rstd * gv[i] + bv[i]);
  *(half4*)orow = o;
}

// ---------------- GEMM: C[m,n] = sum_k A[m,k]*B[n,k] (+bias, epilogue) ----------------
// 1D grid, panel swizzle: GM=16 mt rows per panel, mt varies fastest (L2 A reuse).
// 128x128 tile, BK=64, 4 waves 2x2, 4x4 16x16x32 MFMA per wave. XOR-swizzled LDS.
// All per-iteration address math hoisted: staging offsets (4) and swizzled LDS read
// offsets (16) are loop-invariant; only 2 global base pointers advance per iter.
// EPI: 0 = bias -> fp16; 1 = bias+GELU(tanh) -> fp16; 2 = bias+res -> fp32 (m<MTOK).
template <int EPI>
__global__ __launch_bounds__(256, 3) void gemm_bt(const _Float16* __restrict__ A,
                                                  const _Float16* __restrict__ Bw,
                                                  const float* __restrict__ bias,
                                                  const float* __restrict__ res,
                                                  void* __restrict__ outv, int Ndim, int K) {
  __shared__ __align__(16) _Float16 SH[16384];     // As: [0,8192) Bs: [8192,16384)
  _Float16* As = SH;
  _Float16* Bs = SH + 8192;
  const int GM = 16;
  int nTiles = Ndim >> 7;
  int per = GM * nTiles;
  int lin = blockIdx.x;
  int panel = lin / per;
  int rem = lin - panel * per;
  int gm = MT_TILES - panel * GM; if (gm > GM) gm = GM;
  int mt = panel * GM + rem % gm;
  int nt = rem / gm;
  int t = threadIdx.x, w = t >> 6, l = t & 63;
  int wm = (w >> 1) * 64, wn = (w & 1) * 64;
  int g = l >> 4, li = l & 15;
  float4v acc[4][4] = {};

  // --- loop-invariant staging geometry (per-lane) ---
  long soff[4];
  #pragma unroll
  for (int r = 0; r < 4; ++r) {
    int idx = (w * 4 + r) * 64 + l;        // physical 16B slot id within the tile
    int row = idx >> 3;
    int kc  = (idx & 7) ^ (row & 7);       // XOR swizzle: slot p holds chunk p^(row&7)
    soff[r] = (long)row * K + kc * 8;
  }
  // --- loop-invariant swizzled LDS read offsets ---
  int aro[2][4], bro[2][4];
  #pragma unroll
  for (int ks = 0; ks < 2; ++ks) {
    #pragma unroll
    for (int i = 0; i < 4; ++i) {
      int ar = wm + i * 16 + li;
      aro[ks][i] = ar * 64 + (((ks * 4 + g) ^ (ar & 7)) * 8);
      int br = wn + i * 16 + li;
      bro[ks][i] = br * 64 + (((ks * 4 + g) ^ (br & 7)) * 8);
    }
  }

  const _Float16* ak = A  + (long)mt * 128 * K;
  const _Float16* bk = Bw + (long)nt * 128 * K;
  int nk = K >> 6;
  for (int kt = 0; kt < nk; ++kt) {
    #pragma unroll
    for (int r = 0; r < 4; ++r) {
      gl_lds16(ak + soff[r], As + (w * 4 + r) * 512);
      gl_lds16(bk + soff[r], Bs + (w * 4 + r) * 512);
    }
    ak += 64; bk += 64;
    __syncthreads();
    #pragma unroll
    for (int ks = 0; ks < 2; ++ks) {
      half8 af[4], bf[4];
      #pragma unroll
      for (int i = 0; i < 4; i++) af[i] = *(const half8*)(As + aro[ks][i]);
      #pragma unroll
      for (int j = 0; j < 4; j++) bf[j] = *(const half8*)(Bs + bro[ks][j]);
      #pragma unroll
      for (int i = 0; i < 4; i++)
        #pragma unroll
        for (int j = 0; j < 4; j++)
          acc[i][j] = __builtin_amdgcn_mfma_f32_16x16x32_f16(af[i], bf[j], acc[i][j], 0, 0, 0);
    }
    __syncthreads();
  }
  // epilogue. C/D layout: col=lane&15, row=(lane>>4)*4+reg.
  if (EPI == 2) {
    // fp32 + bias + residual, through LDS: 4 passes of 32 cols, float4 I/O.
    float* Shf = (float*)SH;                       // [128][36] floats = 18 KB
    #pragma unroll
    for (int p = 0; p < 4; ++p) {
      if ((w & 1) == (p >> 1)) {                   // this wave's wn-half owns these cols
        int j0 = (p & 1) * 2;
        #pragma unroll
        for (int i = 0; i < 4; ++i) {
          #pragma unroll
          for (int jj = 0; jj < 2; ++jj) {
            #pragma unroll
            for (int r = 0; r < 4; ++r) {
              int row = wm + i * 16 + g * 4 + r;
              Shf[row * 36 + jj * 16 + li] = acc[i][j0 + jj][r];
            }
          }
        }
      }
      __syncthreads();
      #pragma unroll
      for (int it = 0; it < 4; ++it) {
        int chunk = it * 256 + t;
        int row = chunk >> 3, c4 = chunk & 7;
        int grow = mt * 128 + row;
        if (grow < MTOK) {
          float4v v = *(const float4v*)(Shf + row * 36 + c4 * 4);
          int gcol = nt * 128 + p * 32 + c4 * 4;
          float4v bv = *(const float4v*)(bias + gcol);
          float4v rv = *(const float4v*)(res + (long)grow * Ndim + gcol);
          v = v + bv + rv;
          *(float4v*)((float*)outv + (long)grow * Ndim + gcol) = v;
        }
      }
      __syncthreads();
    }
  } else {
    // fp16 out: LDS transpose, 2 passes of 64 cols; Sh[128][68] (pad 68 = conflict-free)
    _Float16* Sh = SH;
    float bsv[4];
    #pragma unroll
    for (int j = 0; j < 4; ++j) bsv[j] = bias[nt * 128 + wn + j * 16 + li];
    #pragma unroll
    for (int p = 0; p < 2; ++p) {
      if ((w & 1) == p) {
        #pragma unroll
        for (int i = 0; i < 4; ++i) {
          int rl = (w >> 1) * 64 + i * 16 + g * 4;
          #pragma unroll
          for (int j = 0; j < 4; ++j) {
            #pragma unroll
            for (int r = 0; r < 4; ++r) {
              float v = acc[i][j][r] + bsv[j];
              if (EPI == 1) {
                float y = v * (0.79788456f + 0.035677408f * v * v);
                v = v * frcp(1.0f + fexp2(-2.88539008f * y));
              }
              Sh[(rl + r) * 68 + j * 16 + li] = (_Float16)v;
            }
          }
        }
      }
      __syncthreads();
      #pragma unroll
      for (int cc = 0; cc < 4; ++cc) {
        int chunk = cc * 256 + t;
        int row = chunk >> 3, kc8 = chunk & 7;
        half8 hv = *(const half8*)(Sh + row * 68 + kc8 * 8);
        *(half8*)((_Float16*)outv + (long)(mt * 128 + row) * Ndim + nt * 128 + p * 64 + kc8 * 8) = hv;
      }
      __syncthreads();
    }
  }
}

// ---------------- V transpose: Qb V-part [key][d] -> Vt [bh][d][SEQP] fp16 ----------------
__global__ __launch_bounds__(256) void vt_kernel(const _Float16* __restrict__ qkv,
                                                 _Float16* __restrict__ Vt) {
  int kt = blockIdx.x, bh = blockIdx.y;
  int b = bh >> 4, h = bh & 15;
  long base = (long)b * SEQ;
  __shared__ _Float16 Lt[64][72];
  int t = threadIdx.x;
  #pragma unroll
  for (int c = t; c < 512; c += 256) {
    int key = c >> 3, dc = c & 7;
    int kglob = kt * 64 + key;
    half8 v = {};
    if (kglob < SEQ) v = *(const half8*)(qkv + (base + kglob) * 3072 + 2048 + h * 64 + dc * 8);
    *(half8*)(&Lt[key][dc * 8]) = v;
  }
  __syncthreads();
  #pragma unroll
  for (int c = t; c < 512; c += 256) {
    int d = c >> 3, kc = c & 7;
    half8 o;
    #pragma unroll
    for (int j = 0; j < 8; j++) o[j] = Lt[kc * 8 + j][d];
    *(half8*)(Vt + ((long)bh * 64 + d) * SEQP + kt * 64 + kc * 8) = o;
  }
}

// ---------------- Fused attention v2 ----------------
__global__ __launch_bounds__(256) void attn_kernel(const _Float16* __restrict__ qkv,
                                                   const _Float16* __restrict__ Vt,
                                                   _Float16* __restrict__ Y) {
  int qt = blockIdx.x, bh = blockIdx.y;
  int b = bh >> 4, h = bh & 15;
  long base = (long)b * SEQ;
  int t = threadIdx.x, w = t >> 6, l = t & 63;
  int g = l >> 4, li = l & 15;
  __shared__ __align__(16) _Float16 Ks[64 * 64];
  __shared__ __align__(16) _Float16 Vs[64 * 64];
  __shared__ __align__(16) _Float16 Pw[4][32 * 72];
  int q0 = qt * 128 + w * 32;
  half8 qf[2][2];
  #pragma unroll
  for (int m = 0; m < 2; ++m)
    #pragma unroll
    for (int ks = 0; ks < 2; ++ks)
      qf[m][ks] = *(const half8*)(qkv + (base + q0 + m * 16 + li) * 3072 + h * 64 + ks * 32 + g * 8);
  float4v o[2][4] = {};
  float mrow[2][4] = { { -1e30f, -1e30f, -1e30f, -1e30f }, { -1e30f, -1e30f, -1e30f, -1e30f } };
  float lrow[2][4] = {};
  const _Float16* vtb = Vt + (long)bh * 64 * SEQP;
  for (int kt = 0; kt < NKT; ++kt) {
    #pragma unroll
    for (int rr = 0; rr < 2; ++rr) {
      int idx = rr * 256 + w * 64 + l;
      int row = idx >> 3;
      int kc  = (idx & 7) ^ (row & 7);
      gl_lds16(qkv + (base + kt * 64 + row) * 3072 + 1024 + h * 64 + kc * 8,
               Ks + (rr * 256 + w * 64) * 8);
      gl_lds16(vtb + (long)row * SEQP + kt * 64 + kc * 8,
               Vs + (rr * 256 + w * 64) * 8);
    }
    __syncthreads();
    float4v s[2][4] = {};
    #pragma unroll
    for (int ks = 0; ks < 2; ++ks) {
      #pragma unroll
      for (int n = 0; n < 4; ++n) {
        int kr = n * 16 + li;
        half8 kf = *(const half8*)(Ks + kr * 64 + (((ks * 4 + g) ^ (kr & 7)) * 8));
        s[0][n] = __builtin_amdgcn_mfma_f32_16x16x32_f16(qf[0][ks], kf, s[0][n], 0, 0, 0);
        s[1][n] = __builtin_amdgcn_mfma_f32_16x16x32_f16(qf[1][ks], kf, s[1][n], 0, 0, 0);
      }
    }
    bool last = (kt == NKT - 1);
    const float sc = 0.125f * 1.44269504f;
    #pragma unroll
    for (int m = 0; m < 2; ++m) {
      #pragma unroll
      for (int r = 0; r < 4; ++r) {
        float v[4];
        #pragma unroll
        for (int n = 0; n < 4; ++n) {
          v[n] = s[m][n][r] * sc;
          if (last && (kt * 64 + n * 16 + li) >= SEQ) v[n] = -1e30f;
        }
        float a = fmaxf(fmaxf(v[0], v[1]), fmaxf(v[2], v[3]));
        a = fmaxf(a, __shfl_xor(a, 1));
        a = fmaxf(a, __shfl_xor(a, 2));
        a = fmaxf(a, __shfl_xor(a, 4));
        a = fmaxf(a, __shfl_xor(a, 8));
        float mn = fmaxf(mrow[m][r], a);
        float al = fexp2(mrow[m][r] - mn);
        mrow[m][r] = mn;
        int prow = m * 16 + g * 4 + r;
        float rs = 0.f;
        #pragma unroll
        for (int n = 0; n < 4; ++n) {
          float p = fexp2(v[n] - mn);
          rs += p;
          Pw[w][prow * 72 + n * 16 + li] = (_Float16)p;
        }
        rs += __shfl_xor(rs, 1);
        rs += __shfl_xor(rs, 2);
        rs += __shfl_xor(rs, 4);
        rs += __shfl_xor(rs, 8);
        lrow[m][r] = lrow[m][r] * al + rs;
        #pragma unroll
        for (int n = 0; n < 4; ++n) o[m][n][r] *= al;
      }
    }
    #pragma unroll
    for (int ks = 0; ks < 2; ++ks) {
      half8 pa[2];
      #pragma unroll
      for (int m = 0; m < 2; ++m)
        pa[m] = *(const half8*)(&Pw[w][(m * 16 + li) * 72 + ks * 32 + g * 8]);
      #pragma unroll
      for (int n = 0; n < 4; ++n) {
        int vr = n * 16 + li;
        half8 vf = *(const half8*)(Vs + vr * 64 + (((ks * 4 + g) ^ (vr & 7)) * 8));
        o[0][n] = __builtin_amdgcn_mfma_f32_16x16x32_f16(pa[0], vf, o[0][n], 0, 0, 0);
        o[1][n] = __builtin_amdgcn_mfma_f32_16x16x32_f16(pa[1], vf, o[1][n], 0, 0, 0);
      }
    }
    __syncthreads();
  }
  #pragma unroll
  for (int m = 0; m < 2; ++m) {
    #pragma unroll
    for (int r = 0; r < 4; ++r) {
      int qr = q0 + m * 16 + g * 4 + r;
      if (qr < SEQ) {
        float inv = frcp(lrow[m][r]);
        _Float16* yp = Y + (base + qr) * 1024 + h * 64 + li;
        #pragma unroll
        for (int n = 0; n < 4; ++n) yp[n * 16] = (_Float16)(o[m][n][r] * inv);
      }
    }
  }
}

extern "C" void kernel_launch(void* const* d_in, const int* in_sizes, int n_in,
                              void* d_out, int out_size, void* d_ws, size_t ws_size,
                              hipStream_t stream) {
  (void)in_sizes; (void)n_in; (void)out_size; (void)ws_size;
  const float* x      = (const float*)d_in[0];
  const float* w_qkv  = (const float*)d_in[1];
  const float* b_qkv  = (const float*)d_in[2];
  const float* w_proj = (const float*)d_in[3];
  const float* b_proj = (const float*)d_in[4];
  const float* ln1_g  = (const float*)d_in[5];
  const float* ln1_b  = (const float*)d_in[6];
  const float* ln2_g  = (const float*)d_in[7];
  const float* ln2_b  = (const float*)d_in[8];
  const float* w_fc1  = (const float*)d_in[9];
  const float* b_fc1  = (const float*)d_in[10];
  const float* w_fc2  = (const float*)d_in[11];
  const float* b_fc2  = (const float*)d_in[12];

  char* ws = (char*)d_ws;
  _Float16* Abuf = (_Float16*)ws;                          // [MPAD][1024] act fp16
  _Float16* Wq   = (_Float16*)(ws + 19136512);             // weights fp16
  _Float16* Wp   = Wq + 3072 * 1024;
  _Float16* W1   = Wp + 1024 * 1024;
  _Float16* W2   = W1 + 4096 * 1024;
  _Float16* Qb   = (_Float16*)(ws + 44302336);             // [MPAD][3072] qkv fp16
  _Float16* Yb   = Qb + (long)MPAD * 3072;                 // [MPAD][1024] attn out fp16
  _Float16* Hb   = Qb;                                     // [MPAD][4096] fp16, reuses Qb+Yb
  float*    X1   = (float*)(ws + 120848384);               // [MPAD][1024] fp32 x+attn
  _Float16* Vtb  = (_Float16*)(ws + 120848384);            // [256][64][SEQP] fp16, overlays X1

  cvt_all_kernel<<<6144, 256, 0, stream>>>(w_qkv, Wq, w_proj, Wp, w_fc1, W1, w_fc2, W2);

  ln_kernel<<<MPAD, 256, 0, stream>>>(x, ln1_g, ln1_b, Abuf, MTOK);
  gemm_bt<0><<<73 * 24, 256, 0, stream>>>(Abuf, Wq, b_qkv, nullptr, Qb, 3072, 1024);
  vt_kernel<<<dim3(NKT, 256), 256, 0, stream>>>(Qb, Vtb);
  attn_kernel<<<dim3(5, 256), 256, 0, stream>>>(Qb, Vtb, Yb);
  gemm_bt<2><<<73 * 8, 256, 0, stream>>>(Yb, Wp, b_proj, x, X1, 1024, 1024);
  ln_kernel<<<MPAD, 256, 0, stream>>>(X1, ln2_g, ln2_b, Abuf, MTOK);
  gemm_bt<1><<<73 * 32, 256, 0, stream>>>(Abuf, W1, b_fc1, nullptr, Hb, 4096, 1024);
  gemm_bt<2><<<73 * 8, 256, 0, stream>>>(Hb, W2, b_fc2, X1, d_out, 1024, 4096);
}

// Round 8
// 513.889 us; speedup vs baseline: 1.2596x; 1.0614x over previous
//
#include <hip/hip_runtime.h>
#include <cmath>

// Transformer block (ViT): LN1 -> QKV -> MHA -> proj(+res) -> LN2 -> FC1+GELU -> FC2(+res)
// B=16, N=577, C=1024, H=16, D=64, HIDDEN=4096. fp32 in/out, fp16 MFMA compute.
// R1: XOR-swizzled LDS K-chunk placement (GEMM bank conflicts -> 0).
// R2: attention rewrite (gl_lds16 staging, 64-key tiles, exp2 softmax); tanh-GELU.
// R3: GEMM panel swizzle (GM=16) + fp16 epilogue LDS-transpose (full-line half8 stores).
// R4: EPI=2 epilogue through LDS (float4 full-line I/O); single fused cvt kernel.
// R5: hoisted loop-invariant GEMM address math + __launch_bounds__(256,3).
// R6: attention S^T orientation (S^T = K Q^T): key-reduction moves into registers
//     (64 shuffles/iter -> 2), deferred l-sum, alpha via 4 ds_bpermute, packed-half2
//     P round-trip; 64-q blocks (grid 2560) + bh-major grid for XCD L2 locality.
// R7: fix cvt_pkrtz return-type mismatch via __builtin_bit_cast.

#define MTOK 9232            // 16*577 valid token rows
#define MPAD 9344            // 73*128, padded for 128-row GEMM tiles
#define MT_TILES 73
#define SEQ  577
#define SEQP 640             // 10*64 padded key count
#define NKT  10

typedef _Float16 half8  __attribute__((ext_vector_type(8)));
typedef _Float16 half4  __attribute__((ext_vector_type(4)));
typedef _Float16 half2v __attribute__((ext_vector_type(2)));
typedef __fp16   fp16x2 __attribute__((ext_vector_type(2)));
typedef float    float4v __attribute__((ext_vector_type(4)));

__device__ __forceinline__ void gl_lds16(const void* g, void* l) {
  __builtin_amdgcn_global_load_lds((const __attribute__((address_space(1))) void*)g,
                                   (__attribute__((address_space(3))) void*)l, 16, 0, 0);
}

__device__ __forceinline__ float fexp2(float x) { return __builtin_amdgcn_exp2f(x); }
__device__ __forceinline__ float frcp(float x)  { return __builtin_amdgcn_rcpf(x); }
__device__ __forceinline__ float bperm_f(int addr, float v) {
  return __int_as_float(__builtin_amdgcn_ds_bpermute(addr, __float_as_int(v)));
}
__device__ __forceinline__ half2v pack2(float a, float b) {
  fp16x2 p = __builtin_amdgcn_cvt_pkrtz(a, b);
  return __builtin_bit_cast(half2v, p);
}

// ---------------- fp32 -> fp16 convert, all 4 weight mats in one launch ----------------
__global__ __launch_bounds__(256) void cvt_all_kernel(const float* __restrict__ s0, _Float16* __restrict__ d0,
                                                      const float* __restrict__ s1, _Float16* __restrict__ d1,
                                                      const float* __restrict__ s2, _Float16* __restrict__ d2,
                                                      const float* __restrict__ s3, _Float16* __restrict__ d3) {
  int blk = blockIdx.x;
  const float* in; _Float16* out; int base;
  if (blk < 1536)      { in = s0; out = d0; base = blk; }
  else if (blk < 2048) { in = s1; out = d1; base = blk - 1536; }
  else if (blk < 4096) { in = s2; out = d2; base = blk - 2048; }
  else                 { in = s3; out = d3; base = blk - 4096; }
  int i = (base * 256 + threadIdx.x) * 8;
  float4v a = *(const float4v*)(in + i);
  float4v b = *(const float4v*)(in + i + 4);
  half8 o = { (_Float16)a[0], (_Float16)a[1], (_Float16)a[2], (_Float16)a[3],
              (_Float16)b[0], (_Float16)b[1], (_Float16)b[2], (_Float16)b[3] };
  *(half8*)(out + i) = o;
}

// ---------------- LayerNorm: fp32 in -> fp16 out, pad rows zeroed ----------------
__global__ __launch_bounds__(256) void ln_kernel(const float* __restrict__ x,
                                                 const float* __restrict__ gam,
                                                 const float* __restrict__ bet,
                                                 _Float16* __restrict__ out, int mrows) {
  int row = blockIdx.x, t = threadIdx.x;
  _Float16* orow = out + (long)row * 1024 + t * 4;
  if (row >= mrows) { half4 z = {}; *(half4*)orow = z; return; }
  float4v xv = *(const float4v*)(x + (long)row * 1024 + t * 4);
  float s  = xv[0] + xv[1] + xv[2] + xv[3];
  float ss = xv[0]*xv[0] + xv[1]*xv[1] + xv[2]*xv[2] + xv[3]*xv[3];
  #pragma unroll
  for (int o = 32; o > 0; o >>= 1) { s += __shfl_down(s, o); ss += __shfl_down(ss, o); }
  __shared__ float red[8];
  int w = t >> 6;
  if ((t & 63) == 0) { red[w] = s; red[4 + w] = ss; }
  __syncthreads();
  s  = red[0] + red[1] + red[2] + red[3];
  ss = red[4] + red[5] + red[6] + red[7];
  float mean = s * (1.0f / 1024.0f);
  float var  = ss * (1.0f / 1024.0f) - mean * mean;
  float rstd = rsqrtf(var + 1e-5f);
  float4v gv = *(const float4v*)(gam + t * 4);
  float4v bv = *(const float4v*)(bet + t * 4);
  half4 o;
  #pragma unroll
  for (int i = 0; i < 4; i++) o[i] = (_Float16)((xv[i] - mean) * rstd * gv[i] + bv[i]);
  *(half4*)orow = o;
}

// ---------------- GEMM: C[m,n] = sum_k A[m,k]*B[n,k] (+bias, epilogue) ----------------
template <int EPI>
__global__ __launch_bounds__(256, 3) void gemm_bt(const _Float16* __restrict__ A,
                                                  const _Float16* __restrict__ Bw,
                                                  const float* __restrict__ bias,
                                                  const float* __restrict__ res,
                                                  void* __restrict__ outv, int Ndim, int K) {
  __shared__ __align__(16) _Float16 SH[16384];     // As: [0,8192) Bs: [8192,16384)
  _Float16* As = SH;
  _Float16* Bs = SH + 8192;
  const int GM = 16;
  int nTiles = Ndim >> 7;
  int per = GM * nTiles;
  int lin = blockIdx.x;
  int panel = lin / per;
  int rem = lin - panel * per;
  int gm = MT_TILES - panel * GM; if (gm > GM) gm = GM;
  int mt = panel * GM + rem % gm;
  int nt = rem / gm;
  int t = threadIdx.x, w = t >> 6, l = t & 63;
  int wm = (w >> 1) * 64, wn = (w & 1) * 64;
  int g = l >> 4, li = l & 15;
  float4v acc[4][4] = {};

  long soff[4];
  #pragma unroll
  for (int r = 0; r < 4; ++r) {
    int idx = (w * 4 + r) * 64 + l;
    int row = idx >> 3;
    int kc  = (idx & 7) ^ (row & 7);
    soff[r] = (long)row * K + kc * 8;
  }
  int aro[2][4], bro[2][4];
  #pragma unroll
  for (int ks = 0; ks < 2; ++ks) {
    #pragma unroll
    for (int i = 0; i < 4; ++i) {
      int ar = wm + i * 16 + li;
      aro[ks][i] = ar * 64 + (((ks * 4 + g) ^ (ar & 7)) * 8);
      int br = wn + i * 16 + li;
      bro[ks][i] = br * 64 + (((ks * 4 + g) ^ (br & 7)) * 8);
    }
  }

  const _Float16* ak = A  + (long)mt * 128 * K;
  const _Float16* bk = Bw + (long)nt * 128 * K;
  int nk = K >> 6;
  for (int kt = 0; kt < nk; ++kt) {
    #pragma unroll
    for (int r = 0; r < 4; ++r) {
      gl_lds16(ak + soff[r], As + (w * 4 + r) * 512);
      gl_lds16(bk + soff[r], Bs + (w * 4 + r) * 512);
    }
    ak += 64; bk += 64;
    __syncthreads();
    #pragma unroll
    for (int ks = 0; ks < 2; ++ks) {
      half8 af[4], bf[4];
      #pragma unroll
      for (int i = 0; i < 4; i++) af[i] = *(const half8*)(As + aro[ks][i]);
      #pragma unroll
      for (int j = 0; j < 4; j++) bf[j] = *(const half8*)(Bs + bro[ks][j]);
      #pragma unroll
      for (int i = 0; i < 4; i++)
        #pragma unroll
        for (int j = 0; j < 4; j++)
          acc[i][j] = __builtin_amdgcn_mfma_f32_16x16x32_f16(af[i], bf[j], acc[i][j], 0, 0, 0);
    }
    __syncthreads();
  }
  if (EPI == 2) {
    float* Shf = (float*)SH;                       // [128][36] floats
    #pragma unroll
    for (int p = 0; p < 4; ++p) {
      if ((w & 1) == (p >> 1)) {
        int j0 = (p & 1) * 2;
        #pragma unroll
        for (int i = 0; i < 4; ++i) {
          #pragma unroll
          for (int jj = 0; jj < 2; ++jj) {
            #pragma unroll
            for (int r = 0; r < 4; ++r) {
              int row = wm + i * 16 + g * 4 + r;
              Shf[row * 36 + jj * 16 + li] = acc[i][j0 + jj][r];
            }
          }
        }
      }
      __syncthreads();
      #pragma unroll
      for (int it = 0; it < 4; ++it) {
        int chunk = it * 256 + t;
        int row = chunk >> 3, c4 = chunk & 7;
        int grow = mt * 128 + row;
        if (grow < MTOK) {
          float4v v = *(const float4v*)(Shf + row * 36 + c4 * 4);
          int gcol = nt * 128 + p * 32 + c4 * 4;
          float4v bv = *(const float4v*)(bias + gcol);
          float4v rv = *(const float4v*)(res + (long)grow * Ndim + gcol);
          v = v + bv + rv;
          *(float4v*)((float*)outv + (long)grow * Ndim + gcol) = v;
        }
      }
      __syncthreads();
    }
  } else {
    _Float16* Sh = SH;
    float bsv[4];
    #pragma unroll
    for (int j = 0; j < 4; ++j) bsv[j] = bias[nt * 128 + wn + j * 16 + li];
    #pragma unroll
    for (int p = 0; p < 2; ++p) {
      if ((w & 1) == p) {
        #pragma unroll
        for (int i = 0; i < 4; ++i) {
          int rl = (w >> 1) * 64 + i * 16 + g * 4;
          #pragma unroll
          for (int j = 0; j < 4; ++j) {
            #pragma unroll
            for (int r = 0; r < 4; ++r) {
              float v = acc[i][j][r] + bsv[j];
              if (EPI == 1) {
                float y = v * (0.79788456f + 0.035677408f * v * v);
                v = v * frcp(1.0f + fexp2(-2.88539008f * y));
              }
              Sh[(rl + r) * 68 + j * 16 + li] = (_Float16)v;
            }
          }
        }
      }
      __syncthreads();
      #pragma unroll
      for (int cc = 0; cc < 4; ++cc) {
        int chunk = cc * 256 + t;
        int row = chunk >> 3, kc8 = chunk & 7;
        half8 hv = *(const half8*)(Sh + row * 68 + kc8 * 8);
        *(half8*)((_Float16*)outv + (long)(mt * 128 + row) * Ndim + nt * 128 + p * 64 + kc8 * 8) = hv;
      }
      __syncthreads();
    }
  }
}

// ---------------- V transpose: Qb V-part [key][d] -> Vt [bh][d][SEQP] fp16 ----------------
__global__ __launch_bounds__(256) void vt_kernel(const _Float16* __restrict__ qkv,
                                                 _Float16* __restrict__ Vt) {
  int kt = blockIdx.x, bh = blockIdx.y;
  int b = bh >> 4, h = bh & 15;
  long base = (long)b * SEQ;
  __shared__ _Float16 Lt[64][72];
  int t = threadIdx.x;
  #pragma unroll
  for (int c = t; c < 512; c += 256) {
    int key = c >> 3, dc = c & 7;
    int kglob = kt * 64 + key;
    half8 v = {};
    if (kglob < SEQ) v = *(const half8*)(qkv + (base + kglob) * 3072 + 2048 + h * 64 + dc * 8);
    *(half8*)(&Lt[key][dc * 8]) = v;
  }
  __syncthreads();
  #pragma unroll
  for (int c = t; c < 512; c += 256) {
    int d = c >> 3, kc = c & 7;
    half8 o;
    #pragma unroll
    for (int j = 0; j < 8; j++) o[j] = Lt[kc * 8 + j][d];
    *(half8*)(Vt + ((long)bh * 64 + d) * SEQP + kt * 64 + kc * 8) = o;
  }
}

// ---------------- Fused attention v3: S^T orientation ----------------
// Grid (bh, qt): 256 x 10. Block = 64 q (4 waves x 16 q). 64-key tiles.
// S^T = K Q^T via mfma(A=K-frag, B=Q-frag): lane holds (key=g*4+r+16mt, q=li).
// Row-max: 15 in-reg max + 2 shfl_xor(16,32). l-sum: per-lane partial, reduced once
// at the end. alpha -> O lanes via ds_bpermute (invariant addr). P: packed half2
// stores to per-wave Pw[16][40], read back as b128 A-frags per 32-key half.
__global__ __launch_bounds__(256, 4) void attn_kernel(const _Float16* __restrict__ qkv,
                                                      const _Float16* __restrict__ Vt,
                                                      _Float16* __restrict__ Y) {
  int bh = blockIdx.x, qt = blockIdx.y;
  int b = bh >> 4, h = bh & 15;
  long base = (long)b * SEQ;
  int t = threadIdx.x, w = t >> 6, l = t & 63;
  int g = l >> 4, li = l & 15;
  __shared__ __align__(16) _Float16 Ks[64 * 64];
  __shared__ __align__(16) _Float16 Vs[64 * 64];
  __shared__ __align__(16) _Float16 Pw[4][16 * 40];
  int q0 = qt * 64 + w * 16;
  // Q as B-operand (n = q = q0 + li)
  half8 qf[2];
  #pragma unroll
  for (int ks = 0; ks < 2; ++ks)
    qf[ks] = *(const half8*)(qkv + (base + q0 + li) * 3072 + h * 64 + ks * 32 + g * 8);
  float4v o[4] = {};                    // O[q][d]: 4 d-tiles x 4 regs
  float mold = -1e30f, lsum = 0.f;
  int abase = (l & 48);                 // bpermute src byte addr base: 16*g
  const _Float16* vtb = Vt + (long)bh * 64 * SEQP;
  const float sc = 0.125f * 1.44269504f;
  for (int kt = 0; kt < NKT; ++kt) {
    #pragma unroll
    for (int rr = 0; rr < 2; ++rr) {
      int idx = rr * 256 + w * 64 + l;
      int row = idx >> 3;
      int kc  = (idx & 7) ^ (row & 7);
      gl_lds16(qkv + (base + kt * 64 + row) * 3072 + 1024 + h * 64 + kc * 8,
               Ks + (rr * 256 + w * 64) * 8);
      gl_lds16(vtb + (long)row * SEQP + kt * 64 + kc * 8,
               Vs + (rr * 256 + w * 64) * 8);
    }
    __syncthreads();
    // S^T[key][q]: st[mt], key = kt*64 + mt*16 + g*4 + r, q = q0 + li
    float4v st[4] = {};
    #pragma unroll
    for (int ks = 0; ks < 2; ++ks) {
      #pragma unroll
      for (int mt = 0; mt < 4; ++mt) {
        int kr = mt * 16 + li;
        half8 kf = *(const half8*)(Ks + kr * 64 + (((ks * 4 + g) ^ (kr & 7)) * 8));
        st[mt] = __builtin_amdgcn_mfma_f32_16x16x32_f16(kf, qf[ks], st[mt], 0, 0, 0);
      }
    }
    // scale + mask + running max (in-register over 16 keys, then 2 shuffles)
    bool last = (kt == NKT - 1);
    float mx = -1e30f;
    #pragma unroll
    for (int mt = 0; mt < 4; ++mt) {
      #pragma unroll
      for (int r = 0; r < 4; ++r) {
        float v = st[mt][r] * sc;
        if (last && (kt * 64 + mt * 16 + g * 4 + r) >= SEQ) v = -1e30f;
        st[mt][r] = v;
        mx = fmaxf(mx, v);
      }
    }
    mx = fmaxf(mx, __shfl_xor(mx, 16));
    mx = fmaxf(mx, __shfl_xor(mx, 32));
    float mnew = fmaxf(mold, mx);
    float alpha = fexp2(mold - mnew);
    mold = mnew;
    // p = exp2(v - m), per-lane partial sum, pack to half2
    half2v pk[4][2];
    float psum = 0.f;
    #pragma unroll
    for (int mt = 0; mt < 4; ++mt) {
      float p0 = fexp2(st[mt][0] - mnew);
      float p1 = fexp2(st[mt][1] - mnew);
      float p2 = fexp2(st[mt][2] - mnew);
      float p3 = fexp2(st[mt][3] - mnew);
      psum += (p0 + p1) + (p2 + p3);
      pk[mt][0] = pack2(p0, p1);
      pk[mt][1] = pack2(p2, p3);
    }
    lsum = lsum * alpha + psum;
    // alpha to O lanes (O row q = g*4+r): src lane = g*4+r
    float ab[4];
    #pragma unroll
    for (int r = 0; r < 4; ++r) ab[r] = bperm_f(abase + 4 * r, alpha);
    #pragma unroll
    for (int nd = 0; nd < 4; ++nd)
      #pragma unroll
      for (int r = 0; r < 4; ++r) o[nd][r] *= ab[r];
    // PV in 32-key halves: write P^T half -> read A-frag -> MFMA
    #pragma unroll
    for (int ks = 0; ks < 2; ++ks) {
      #pragma unroll
      for (int mtl = 0; mtl < 2; ++mtl) {
        int mt = 2 * ks + mtl;
        *(half2v*)(&Pw[w][li * 40 + mtl * 16 + g * 4])     = pk[mt][0];
        *(half2v*)(&Pw[w][li * 40 + mtl * 16 + g * 4 + 2]) = pk[mt][1];
      }
      half8 pa = *(const half8*)(&Pw[w][li * 40 + g * 8]);
      #pragma unroll
      for (int nd = 0; nd < 4; ++nd) {
        int vr = nd * 16 + li;
        half8 vf = *(const half8*)(Vs + vr * 64 + (((ks * 4 + g) ^ (vr & 7)) * 8));
        o[nd] = __builtin_amdgcn_mfma_f32_16x16x32_f16(pa, vf, o[nd], 0, 0, 0);
      }
    }
    __syncthreads();
  }
  // final: reduce l across the 4 g-lanes, bpermute 1/l to O lanes, write Y
  lsum += __shfl_xor(lsum, 16);
  lsum += __shfl_xor(lsum, 32);
  float linv = frcp(lsum);
  float lb[4];
  #pragma unroll
  for (int r = 0; r < 4; ++r) lb[r] = bperm_f(abase + 4 * r, linv);
  #pragma unroll
  for (int r = 0; r < 4; ++r) {
    int qr = qt * 64 + w * 16 + g * 4 + r;
    if (qr < SEQ) {
      _Float16* yp = Y + (base + qr) * 1024 + h * 64 + li;
      #pragma unroll
      for (int nd = 0; nd < 4; ++nd) yp[nd * 16] = (_Float16)(o[nd][r] * lb[r]);
    }
  }
}

extern "C" void kernel_launch(void* const* d_in, const int* in_sizes, int n_in,
                              void* d_out, int out_size, void* d_ws, size_t ws_size,
                              hipStream_t stream) {
  (void)in_sizes; (void)n_in; (void)out_size; (void)ws_size;
  const float* x      = (const float*)d_in[0];
  const float* w_qkv  = (const float*)d_in[1];
  const float* b_qkv  = (const float*)d_in[2];
  const float* w_proj = (const float*)d_in[3];
  const float* b_proj = (const float*)d_in[4];
  const float* ln1_g  = (const float*)d_in[5];
  const float* ln1_b  = (const float*)d_in[6];
  const float* ln2_g  = (const float*)d_in[7];
  const float* ln2_b  = (const float*)d_in[8];
  const float* w_fc1  = (const float*)d_in[9];
  const float* b_fc1  = (const float*)d_in[10];
  const float* w_fc2  = (const float*)d_in[11];
  const float* b_fc2  = (const float*)d_in[12];

  char* ws = (char*)d_ws;
  _Float16* Abuf = (_Float16*)ws;                          // [MPAD][1024] act fp16
  _Float16* Wq   = (_Float16*)(ws + 19136512);             // weights fp16
  _Float16* Wp   = Wq + 3072 * 1024;
  _Float16* W1   = Wp + 1024 * 1024;
  _Float16* W2   = W1 + 4096 * 1024;
  _Float16* Qb   = (_Float16*)(ws + 44302336);             // [MPAD][3072] qkv fp16
  _Float16* Yb   = Qb + (long)MPAD * 3072;                 // [MPAD][1024] attn out fp16
  _Float16* Hb   = Qb;                                     // [MPAD][4096] fp16, reuses Qb+Yb
  float*    X1   = (float*)(ws + 120848384);               // [MPAD][1024] fp32 x+attn
  _Float16* Vtb  = (_Float16*)(ws + 120848384);            // [256][64][SEQP] fp16, overlays X1

  cvt_all_kernel<<<6144, 256, 0, stream>>>(w_qkv, Wq, w_proj, Wp, w_fc1, W1, w_fc2, W2);

  ln_kernel<<<MPAD, 256, 0, stream>>>(x, ln1_g, ln1_b, Abuf, MTOK);
  gemm_bt<0><<<73 * 24, 256, 0, stream>>>(Abuf, Wq, b_qkv, nullptr, Qb, 3072, 1024);
  vt_kernel<<<dim3(NKT, 256), 256, 0, stream>>>(Qb, Vtb);
  attn_kernel<<<dim3(256, NKT), 256, 0, stream>>>(Qb, Vtb, Yb);
  gemm_bt<2><<<73 * 8, 256, 0, stream>>>(Yb, Wp, b_proj, x, X1, 1024, 1024);
  ln_kernel<<<MPAD, 256, 0, stream>>>(X1, ln2_g, ln2_b, Abuf, MTOK);
  gemm_bt<1><<<73 * 32, 256, 0, stream>>>(Abuf, W1, b_fc1, nullptr, Hb, 4096, 1024);
  gemm_bt<2><<<73 * 8, 256, 0, stream>>>(Hb, W2, b_fc2, X1, d_out, 1024, 4096);
}